// Round 14
// baseline (263.126 us; speedup 1.0000x reference)
//
#include <hip/hip_runtime.h>
#include <hip/hip_bf16.h>
#include <cstdint>

#define NHEAD 16
#define DHEAD 128
#define DMODEL 2048
#define TSEQ 2048
#define BATCH 2

using bf16 = __hip_bfloat16;
typedef __attribute__((ext_vector_type(4)))  float f32x4;
typedef __attribute__((ext_vector_type(16))) float f32x16;
typedef __attribute__((ext_vector_type(2)))  float f32x2;
typedef __attribute__((ext_vector_type(4)))  float float4_t;
typedef __attribute__((ext_vector_type(4)))  short s16x4;
typedef __bf16 bf16x8 __attribute__((ext_vector_type(8)));

#define GLOAD_LDS16(gptr, lptr)                                                        \
  __builtin_amdgcn_global_load_lds((const __attribute__((address_space(1))) void*)(gptr), \
                                   (__attribute__((address_space(3))) void*)(lptr), 16, 0, 0)

#if __has_builtin(__builtin_amdgcn_exp2f)
#define EXP2(x) __builtin_amdgcn_exp2f(x)
#else
#define EXP2(x) exp2f(x)
#endif

__device__ __forceinline__ float bf2f(bf16 v) { return __bfloat162float(v); }
__device__ __forceinline__ bf16  f2bf(float f) { return __float2bfloat16(f); }
__device__ __forceinline__ unsigned short bfbits(float f) {
  return __builtin_bit_cast(unsigned short, f2bf(f));
}
__device__ __forceinline__ unsigned int pack2(float a, float b) {
  return (unsigned int)bfbits(a) | ((unsigned int)bfbits(b) << 16);
}

// ---------------------------------------------------------------- fused cast fp32 -> bf16 (all three inputs)
#define N4_X  (4096 * 2048 / 4)
#define N4_WQ (6144 * 2048 / 4)
#define N4_WO (2048 * 2048 / 4)
__global__ void cast_all(const float* __restrict__ x, const float* __restrict__ wq,
                         const float* __restrict__ wo, unsigned short* __restrict__ xb,
                         unsigned short* __restrict__ wqb, unsigned short* __restrict__ wob) {
  const int total = N4_X + N4_WQ + N4_WO;
  int stride = gridDim.x * blockDim.x;
  for (int i = blockIdx.x * blockDim.x + threadIdx.x; i < total; i += stride) {
    const float* src;
    unsigned short* dst;
    int j;
    if (i < N4_X)            { src = x;  dst = xb;  j = i; }
    else if (i < N4_X + N4_WQ) { src = wq; dst = wqb; j = i - N4_X; }
    else                     { src = wo; dst = wob; j = i - N4_X - N4_WQ; }
    float4_t v = reinterpret_cast<const float4_t*>(src)[j];
    s16x4 r;
    r.x = (short)bfbits(v.x);
    r.y = (short)bfbits(v.y);
    r.z = (short)bfbits(v.z);
    r.w = (short)bfbits(v.w);
    reinterpret_cast<s16x4*>(dst)[j] = r;
  }
}

// ---------------------------------------------------------------- RoPE tables (fp32 packed, [T][64] of (cos,sin))
__global__ void rope_tables(f32x2* __restrict__ cstab) {
  int i = blockIdx.x * blockDim.x + threadIdx.x;
  if (i >= TSEQ * 64) return;
  int t = i >> 6, f = i & 63;
  float inv = __expf(-((2.0f * (float)f) / 128.0f) * logf(10000.0f));
  float ang = (float)t * inv;
  f32x2 cs;
  cs.x = cosf(ang);
  cs.y = sinf(ang);
  cstab[i] = cs;
}

// ---------------------------------------------------------------- C store helpers
__device__ __forceinline__ void store_c(float* p, float v) { *p = v; }
__device__ __forceinline__ void store_c(unsigned short* p, float v) { *p = bfbits(v); }

// ---------------------------------------------------------------- bf16 GEMM, C = A(MxK) * B(NxK)^T
// r13 structure (BK=64, 128-B LDS rows, 8-chunk XOR swizzle, 2 barriers/K-tile)
// with mfma_f32_32x32x16_bf16 fragments (µbench 2382 vs 2075 TF for 16x16):
//   A/B operand: row = lane&31, k = ks*16 + (lane>>5)*8 + i  (chunk ks*2+hi, XOR'd)
//   C/D (m74/m101): col = lane&31, row = (r&3) + 8*(r>>2) + 4*(lane>>5)
// Wave tile 32 x 128 (1 M-frag x 4 N-frags). 16 MFMA + 20 ds_read per K-tile.
// ROPE: rotary on q,k thirds (q pre-scaled by (1/sqrt(DH))*log2e); head-dim pos
//   p = ni*32+(lane&31), pair (p, p+64) = frags (ni, ni+2) — in-lane.
// VT: v third stored transposed into vt[(b*16+h)*128+d][t] (regs 4g..4g+3 are
//   4 consecutive rows -> s16x4 packs).
template <typename CT, bool ROPE, bool VT>
__global__ __launch_bounds__(256, 2) void gemm_bt(const unsigned short* __restrict__ A,
                                                  const unsigned short* __restrict__ B,
                                                  CT* __restrict__ C, int M, int N, int K,
                                                  const f32x2* __restrict__ cstab,
                                                  unsigned short* __restrict__ vt) {
  __shared__ __align__(16) unsigned short As[128 * 64];   // 16 KB
  __shared__ __align__(16) unsigned short Bs[128 * 64];   // 16 KB
  const int tid  = threadIdx.x;
  const int wave = tid >> 6, lane = tid & 63;
  const int l31 = lane & 31, hi = lane >> 5;
  const int m0 = blockIdx.x * 128, n0 = blockIdx.y * 128;
  const int wm = wave * 32;
  f32x16 acc[4] = {};   // N-frags 0..3 (n = ni*32 + l31)

  // fragment read: row R, k-slice ks (16 k each): chunk = (ks*2 + hi) ^ (R & 7)
#define RD32(BASE, R, ks)                                                       \
  (*reinterpret_cast<const bf16x8*>(                                            \
      (const char*)(BASE) + (R) * 128 + (((((ks) << 1) + hi) ^ ((R) & 7)) << 4)))

  for (int k0 = 0; k0 < K; k0 += 64) {
    // stage 128x64 of A and B: 1024 chunks each, 4/thread; linear dest, swizzled src
#pragma unroll
    for (int it = 0; it < 4; ++it) {
      int CC = it * 256 + tid;
      int R = CC >> 3, ch = CC & 7;
      int kg = (ch ^ (R & 7)) << 3;
      GLOAD_LDS16(A + (size_t)(m0 + R) * K + k0 + kg, (char*)As + CC * 16);
      GLOAD_LDS16(B + (size_t)(n0 + R) * K + k0 + kg, (char*)Bs + CC * 16);
    }
    __syncthreads();
#pragma unroll
    for (int ks = 0; ks < 4; ++ks) {
      bf16x8 af = RD32(As, wm + l31, ks);
      bf16x8 bfr[4];
#pragma unroll
      for (int ni = 0; ni < 4; ++ni)
        bfr[ni] = RD32(Bs, ni * 32 + l31, ks);
#pragma unroll
      for (int ni = 0; ni < 4; ++ni)
        acc[ni] = __builtin_amdgcn_mfma_f32_32x32x16_bf16(af, bfr[ni], acc[ni], 0, 0, 0);
    }
    __syncthreads();
  }
#undef RD32

  if (ROPE && n0 < 2 * DMODEL) {
    const float qsc = (n0 < DMODEL) ? 0.12751743f : 1.0f;   // 1/sqrt(128) * log2e for q
#pragma unroll
    for (int ni = 0; ni < 2; ++ni) {
      const int f = ni * 32 + l31;   // 0..63
#pragma unroll
      for (int r = 0; r < 16; ++r) {
        const int row = m0 + wm + (r & 3) + 8 * (r >> 2) + 4 * hi;
        const int t = row & (TSEQ - 1);
        const f32x2 cs = cstab[t * 64 + f];
        const float a1 = acc[ni][r];
        const float a2 = acc[ni + 2][r];
        store_c(C + (size_t)row * N + n0 + f,      (a1 * cs.x - a2 * cs.y) * qsc);
        store_c(C + (size_t)row * N + n0 + f + 64, (a2 * cs.x + a1 * cs.y) * qsc);
      }
    }
  } else if (VT) {
    // v third: store transposed into vt[(b*16+h)*128 + d][t]; regs 4g..4g+3 are
    // rows {8g+4hi + 0..3} -> one s16x4 of 4 consecutive t.
    const int h = (n0 - 2 * DMODEL) >> 7;
#pragma unroll
    for (int ni = 0; ni < 4; ++ni) {
      const int d = ni * 32 + l31;
#pragma unroll
      for (int g = 0; g < 4; ++g) {
        const int r0 = m0 + wm + 8 * g + 4 * hi;
        const int b = r0 >> 11, t0 = r0 & (TSEQ - 1);
        s16x4 v4;
#pragma unroll
        for (int j = 0; j < 4; ++j) v4[j] = (short)bfbits(acc[ni][g * 4 + j]);
        *reinterpret_cast<s16x4*>(
            vt + (size_t)((b * NHEAD + h) * DHEAD + d) * TSEQ + t0) = v4;
      }
    }
  } else {
#pragma unroll
    for (int ni = 0; ni < 4; ++ni)
#pragma unroll
      for (int r = 0; r < 16; ++r) {
        const int row = m0 + wm + (r & 3) + 8 * (r >> 2) + 4 * hi;
        const int c = n0 + ni * 32 + l31;
        store_c(C + (size_t)row * N + c, acc[ni][r]);
      }
  }
}

// ---------------------------------------------------------------- flash attention (causal) — r12/r13 verified
// 8 waves x 16 q-rows; KV staged once per block, double-buffered, XOR-swizzled.
// Complementary CU-pair balance: x = b ? 15-raw : raw.
__global__ __launch_bounds__(512, 4) void flash_attn(const unsigned short* __restrict__ qkv,
                                                     const unsigned short* __restrict__ vt,
                                                     unsigned short* __restrict__ out) {
  __shared__ unsigned short kb[2][64 * 128];
  __shared__ unsigned short vb[2][128 * 64];
  __shared__ unsigned short plds[8][16 * 64];

  const int tid  = threadIdx.x;
  const int wave = tid >> 6, lane = tid & 63;
  const int lrow = lane >> 4, lcol = lane & 15;
  const int h = blockIdx.y, b = blockIdx.z;
  const int x = b ? (15 - (int)blockIdx.x) : (int)blockIdx.x;
  const int q0b = x * 128;
  const int q0w = q0b + wave * 16;
  const size_t qkbase = (size_t)b * TSEQ * (3 * DMODEL);
  const unsigned short* kptr = qkv + qkbase + DMODEL + h * DHEAD;
  const unsigned short* vptr = vt + (size_t)((b * NHEAD + h) * DHEAD) * TSEQ;

  bf16x8 qf[4];
#pragma unroll
  for (int kk = 0; kk < 4; ++kk)
    qf[kk] = *reinterpret_cast<const bf16x8*>(
        qkv + qkbase + (size_t)(q0w + lcol) * (3 * DMODEL) + h * DHEAD + kk * 32 + lrow * 8);

  f32x4 o[8] = {};
  float m = -1.0e30f, l = 0.f;

  const int nsteps = 2 * x + 2;

#define STAGE_KV(bi, kv0s)                                                              \
  {                                                                                     \
    _Pragma("unroll")                                                                   \
    for (int c = 0; c < 2; ++c) {                                                       \
      int cc = c * 512 + tid;                                                           \
      int krow = cc >> 4, kchk = (cc & 15) ^ (krow & 7);                                \
      GLOAD_LDS16(kptr + (size_t)((kv0s) + krow) * (3 * DMODEL) + kchk * 8,             \
                  &kb[bi][cc * 8]);                                                     \
      int vrow = cc >> 3, vchk = (cc & 7) ^ (vrow & 7);                                 \
      GLOAD_LDS16(vptr + (size_t)vrow * TSEQ + (kv0s) + vchk * 8,                       \
                  &vb[bi][cc * 8]);                                                     \
    }                                                                                   \
  }

  STAGE_KV(0, 0);
  __syncthreads();

  int cur = 0;
  for (int s = 0; s < nsteps; ++s) {
    const int kv0 = s * 64;
    if (s + 1 < nsteps) STAGE_KV(cur ^ 1, kv0 + 64);

    if (kv0 <= q0w + 15) {
      const unsigned short* kbc = kb[cur];
      const unsigned short* vbc = vb[cur];

      f32x4 sc[4] = {};
      __builtin_amdgcn_s_setprio(1);
#pragma unroll
      for (int n = 0; n < 4; ++n) {
        const int r = n * 16 + lcol;
#pragma unroll
        for (int kk = 0; kk < 4; ++kk) {
          bf16x8 kf = *reinterpret_cast<const bf16x8*>(
              &kbc[r * 128 + (((kk * 4 + lrow) ^ (lcol & 7)) << 3)]);
          sc[n] = __builtin_amdgcn_mfma_f32_16x16x32_bf16(kf, qf[kk], sc[n], 0, 0, 0);
        }
      }
      __builtin_amdgcn_s_setprio(0);

      const bool diag = (kv0 + 63 > q0w);
      const int qi = q0w + lcol;
      float sv[16];
#pragma unroll
      for (int n = 0; n < 4; ++n)
#pragma unroll
        for (int j = 0; j < 4; ++j) {
          float v = sc[n][j];
          if (diag && (kv0 + n * 16 + lrow * 4 + j) > qi) v = -1.0e30f;
          sv[n * 4 + j] = v;
        }
      float t8[8];
#pragma unroll
      for (int j = 0; j < 8; ++j) t8[j] = fmaxf(sv[j], sv[j + 8]);
#pragma unroll
      for (int j = 0; j < 4; ++j) t8[j] = fmaxf(t8[j], t8[j + 4]);
      float pm = fmaxf(fmaxf(t8[0], t8[1]), fmaxf(t8[2], t8[3]));
      pm = fmaxf(pm, __shfl_xor(pm, 16));
      pm = fmaxf(pm, __shfl_xor(pm, 32));

      if (__any(pm > m + 11.5f)) {   // defer-max (T13, THR = 8 nats = 11.5 log2)
        const float mn  = fmaxf(m, pm);
        const float fsc = EXP2(m - mn);
        m = mn;
        l *= fsc;
#pragma unroll
        for (int c = 0; c < 8; ++c) o[c] *= fsc;
      }

#pragma unroll
      for (int i = 0; i < 16; ++i) sv[i] = EXP2(sv[i] - m);
      float a8[8];
#pragma unroll
      for (int j = 0; j < 8; ++j) a8[j] = sv[j] + sv[j + 8];
#pragma unroll
      for (int j = 0; j < 4; ++j) a8[j] += a8[j + 4];
      float rs = (a8[0] + a8[1]) + (a8[2] + a8[3]);
      rs += __shfl_xor(rs, 16);
      rs += __shfl_xor(rs, 32);
      l += rs;

      char* pw = reinterpret_cast<char*>(&plds[wave][0]);
#pragma unroll
      for (int n = 0; n < 4; ++n)
#pragma unroll
        for (int j = 0; j < 4; j += 2) {
          int boff = (lcol << 7) + ((((n << 1) + (lrow >> 1)) ^ (lcol & 7)) << 4) +
                     ((lrow & 1) << 3) + (j << 1);
          *reinterpret_cast<unsigned int*>(pw + boff) = pack2(sv[n * 4 + j], sv[n * 4 + j + 1]);
        }
      asm volatile("s_waitcnt lgkmcnt(0)" ::: "memory");

      bf16x8 pf0 = *reinterpret_cast<const bf16x8*>(
          pw + (lcol << 7) + ((lrow ^ (lcol & 7)) << 4));
      bf16x8 pf1 = *reinterpret_cast<const bf16x8*>(
          pw + (lcol << 7) + (((4 + lrow) ^ (lcol & 7)) << 4));

      __builtin_amdgcn_s_setprio(1);
#pragma unroll
      for (int c = 0; c < 8; ++c) {
        const int d = c * 16 + lcol;
        bf16x8 vf0 = *reinterpret_cast<const bf16x8*>(
            &vbc[d * 64 + ((lrow ^ (lcol & 7)) << 3)]);
        o[c] = __builtin_amdgcn_mfma_f32_16x16x32_bf16(vf0, pf0, o[c], 0, 0, 0);
        bf16x8 vf1 = *reinterpret_cast<const bf16x8*>(
            &vbc[d * 64 + (((4 + lrow) ^ (lcol & 7)) << 3)]);
        o[c] = __builtin_amdgcn_mfma_f32_16x16x32_bf16(vf1, pf1, o[c], 0, 0, 0);
      }
      __builtin_amdgcn_s_setprio(0);
    }

    __syncthreads();
    cur ^= 1;
  }

  const float rl = 1.0f / l;
  const int trow = q0w + lcol;
#pragma unroll
  for (int c = 0; c < 8; ++c) {
    s16x4 st;
#pragma unroll
    for (int j = 0; j < 4; ++j) st[j] = (short)bfbits(o[c][j] * rl);
    *reinterpret_cast<s16x4*>(
        out + (size_t)(b * TSEQ + trow) * DMODEL + h * DHEAD + c * 16 + lrow * 4) = st;
  }
#undef STAGE_KV
}

// ---------------------------------------------------------------- launcher
extern "C" void kernel_launch(void* const* d_in, const int* in_sizes, int n_in,
                              void* d_out, int out_size, void* d_ws, size_t ws_size,
                              hipStream_t stream) {
  const float* x     = (const float*)d_in[0];
  const float* w_qkv = (const float*)d_in[1];
  const float* w_op  = (const float*)d_in[2];
  float* out = (float*)d_out;

  const size_t SZ_XB  = (size_t)4096 * 2048 * 2;
  const size_t SZ_WQ  = (size_t)6144 * 2048 * 2;
  const size_t SZ_WO  = (size_t)2048 * 2048 * 2;
  const size_t SZ_QKV = (size_t)4096 * 6144 * 2;
  const size_t SZ_VT  = (size_t)32 * 128 * 2048 * 2;
  const size_t SZ_AO  = (size_t)4096 * 2048 * 2;
  const size_t SZ_TAB = (size_t)2048 * 64 * 8;
  const size_t NEEDED = SZ_XB + SZ_WQ + SZ_WO + SZ_QKV + SZ_VT + SZ_AO + SZ_TAB;
  if (ws_size < NEEDED) return;

  char* p = (char*)d_ws;
  unsigned short* xb   = (unsigned short*)p; p += SZ_XB;
  unsigned short* wqb  = (unsigned short*)p; p += SZ_WQ;
  unsigned short* wob  = (unsigned short*)p; p += SZ_WO;
  unsigned short* qkv  = (unsigned short*)p; p += SZ_QKV;
  unsigned short* vt   = (unsigned short*)p; p += SZ_VT;
  unsigned short* ao   = (unsigned short*)p; p += SZ_AO;
  f32x2* cstab = (f32x2*)p; p += SZ_TAB;

  cast_all<<<dim3(2048), dim3(256), 0, stream>>>(x, w_qkv, w_op, xb, wqb, wob);
  rope_tables<<<dim3(512), dim3(256), 0, stream>>>(cstab);

  // qkv = x @ w_qkv^T with fused RoPE (+ q scale * log2e) on q,k thirds and
  // fused transposed V store (v third -> vt directly)
  gemm_bt<unsigned short, true, true><<<dim3(32, 48), dim3(256), 0, stream>>>(
      xb, wqb, qkv, 4096, 6144, 2048, cstab, vt);
  // causal flash attention (512 blocks, all-resident, CU-pair balanced)
  flash_attn<<<dim3(16, 16, 2), dim3(512), 0, stream>>>(qkv, vt, ao);
  // out = attn_out @ w_op^T
  gemm_bt<float, false, false><<<dim3(32, 16), dim3(256), 0, stream>>>(
      ao, wob, out, 4096, 2048, 2048, nullptr, nullptr);
}

// Round 15
// 254.758 us; speedup vs baseline: 1.0328x; 1.0328x over previous
//
#include <hip/hip_runtime.h>
#include <hip/hip_bf16.h>
#include <cstdint>

#define NHEAD 16
#define DHEAD 128
#define DMODEL 2048
#define TSEQ 2048
#define BATCH 2

using bf16 = __hip_bfloat16;
typedef __attribute__((ext_vector_type(4))) float  f32x4;
typedef __attribute__((ext_vector_type(2))) float  f32x2;
typedef __attribute__((ext_vector_type(4))) float  float4_t;
typedef __attribute__((ext_vector_type(4))) short  s16x4;
typedef __bf16 bf16x8 __attribute__((ext_vector_type(8)));

#define GLOAD_LDS16(gptr, lptr)                                                        \
  __builtin_amdgcn_global_load_lds((const __attribute__((address_space(1))) void*)(gptr), \
                                   (__attribute__((address_space(3))) void*)(lptr), 16, 0, 0)

#if __has_builtin(__builtin_amdgcn_exp2f)
#define EXP2(x) __builtin_amdgcn_exp2f(x)
#else
#define EXP2(x) exp2f(x)
#endif

__device__ __forceinline__ float bf2f(bf16 v) { return __bfloat162float(v); }
__device__ __forceinline__ bf16  f2bf(float f) { return __float2bfloat16(f); }
__device__ __forceinline__ unsigned short bfbits(float f) {
  return __builtin_bit_cast(unsigned short, f2bf(f));
}
__device__ __forceinline__ unsigned int pack2(float a, float b) {
  return (unsigned int)bfbits(a) | ((unsigned int)bfbits(b) << 16);
}

// ---------------------------------------------------------------- fused cast fp32 -> bf16 (all three inputs)
#define N4_X  (4096 * 2048 / 4)
#define N4_WQ (6144 * 2048 / 4)
#define N4_WO (2048 * 2048 / 4)
__global__ void cast_all(const float* __restrict__ x, const float* __restrict__ wq,
                         const float* __restrict__ wo, unsigned short* __restrict__ xb,
                         unsigned short* __restrict__ wqb, unsigned short* __restrict__ wob) {
  const int total = N4_X + N4_WQ + N4_WO;
  int stride = gridDim.x * blockDim.x;
  for (int i = blockIdx.x * blockDim.x + threadIdx.x; i < total; i += stride) {
    const float* src;
    unsigned short* dst;
    int j;
    if (i < N4_X)            { src = x;  dst = xb;  j = i; }
    else if (i < N4_X + N4_WQ) { src = wq; dst = wqb; j = i - N4_X; }
    else                     { src = wo; dst = wob; j = i - N4_X - N4_WQ; }
    float4_t v = reinterpret_cast<const float4_t*>(src)[j];
    s16x4 r;
    r.x = (short)bfbits(v.x);
    r.y = (short)bfbits(v.y);
    r.z = (short)bfbits(v.z);
    r.w = (short)bfbits(v.w);
    reinterpret_cast<s16x4*>(dst)[j] = r;
  }
}

// ---------------------------------------------------------------- RoPE tables (fp32 packed, [T][64] of (cos,sin))
__global__ void rope_tables(f32x2* __restrict__ cstab) {
  int i = blockIdx.x * blockDim.x + threadIdx.x;
  if (i >= TSEQ * 64) return;
  int t = i >> 6, f = i & 63;
  float inv = __expf(-((2.0f * (float)f) / 128.0f) * logf(10000.0f));
  float ang = (float)t * inv;
  f32x2 cs;
  cs.x = cosf(ang);
  cs.y = sinf(ang);
  cstab[i] = cs;
}

// ---------------------------------------------------------------- C store helpers
__device__ __forceinline__ void store_c(float* p, float v) { *p = v; }
__device__ __forceinline__ void store_c(unsigned short* p, float v) { *p = bfbits(v); }

// ---------------------------------------------------------------- bf16 GEMM, C = A(MxK) * B(NxK)^T
// r13-verified core (BK=64, 128-B LDS rows, 8-chunk XOR swizzle, 16x16x32 MFMA,
// 0 bank conflicts, 946 TF) + T3-minimum double-buffer: stage tile t+1 BEFORE
// computing tile t, ONE __syncthreads per K-tile (drain covered by compute).
// Race audit: compute reads buf[t&1], staging writes buf[(t+1)&1] (disjoint);
// end-of-iter barrier orders buffer reuse across waves.
// ROPE: rotary on q,k thirds (q pre-scaled by (1/sqrt(DH))*log2e).
// VT: v third stored transposed into vt[(b*16+h)*128+d][t].
template <typename CT, bool ROPE, bool VT>
__global__ __launch_bounds__(256, 2) void gemm_bt(const unsigned short* __restrict__ A,
                                                  const unsigned short* __restrict__ B,
                                                  CT* __restrict__ C, int M, int N, int K,
                                                  const f32x2* __restrict__ cstab,
                                                  unsigned short* __restrict__ vt) {
  __shared__ __align__(16) unsigned short As[2][128 * 64];   // 32 KB
  __shared__ __align__(16) unsigned short Bs[2][128 * 64];   // 32 KB
  const int tid  = threadIdx.x;
  const int wave = tid >> 6, lane = tid & 63;
  const int m0 = blockIdx.x * 128, n0 = blockIdx.y * 128;
  const int wm = wave * 32;
  const int lrow = lane >> 4, lcol = lane & 15;
  f32x4 acc[2][8] = {};

  // fragment read: row R, k-half ks: chunk = (ks*4 + lrow) ^ (R & 7)
#define RD_FRAG(BASE, R, ks)                                                    \
  (*reinterpret_cast<const bf16x8*>(                                            \
      (const char*)(BASE) + (R) * 128 + (((((ks) << 2) + lrow) ^ ((R) & 7)) << 4)))

  // stage 128x64 of A and B into buffer bi: 1024 chunks each, 4/thread;
  // linear LDS dest, pre-swizzled global source (^= row&7)
#define STAGE_AB(bi, k0)                                                        \
  {                                                                             \
    _Pragma("unroll")                                                           \
    for (int it = 0; it < 4; ++it) {                                            \
      int CC = it * 256 + tid;                                                  \
      int R = CC >> 3, ch = CC & 7;                                             \
      int kg = (ch ^ (R & 7)) << 3;                                             \
      GLOAD_LDS16(A + (size_t)(m0 + R) * K + (k0) + kg, (char*)As[bi] + CC * 16); \
      GLOAD_LDS16(B + (size_t)(n0 + R) * K + (k0) + kg, (char*)Bs[bi] + CC * 16); \
    }                                                                           \
  }

  const int NTK = K >> 6;
  STAGE_AB(0, 0);
  __syncthreads();

  for (int t = 0; t < NTK; ++t) {
    if (t + 1 < NTK) STAGE_AB((t + 1) & 1, (t + 1) << 6);   // prefetch next tile
    const char* Ab = (const char*)As[t & 1];
    const char* Bb = (const char*)Bs[t & 1];
#pragma unroll
    for (int ks = 0; ks < 2; ++ks) {
      bf16x8 af[2], bfr[8];
#pragma unroll
      for (int mi = 0; mi < 2; ++mi)
        af[mi] = RD_FRAG(Ab, wm + mi * 16 + lcol, ks);
#pragma unroll
      for (int ni = 0; ni < 8; ++ni)
        bfr[ni] = RD_FRAG(Bb, ni * 16 + lcol, ks);
#pragma unroll
      for (int mi = 0; mi < 2; ++mi)
#pragma unroll
        for (int ni = 0; ni < 8; ++ni)
          acc[mi][ni] = __builtin_amdgcn_mfma_f32_16x16x32_bf16(af[mi], bfr[ni], acc[mi][ni], 0, 0, 0);
    }
    __syncthreads();   // drains staging vmcnt (covered by compute) + orders buffer reuse
  }
#undef RD_FRAG
#undef STAGE_AB

  if (ROPE && n0 < 2 * DMODEL) {
    const float qsc = (n0 < DMODEL) ? 0.12751743f : 1.0f;   // 1/sqrt(128) * log2e for q
#pragma unroll
    for (int mi = 0; mi < 2; ++mi)
#pragma unroll
      for (int j = 0; j < 4; ++j) {
        const int r = m0 + wm + mi * 16 + lrow * 4 + j;
        const int t = r & (TSEQ - 1);
#pragma unroll
        for (int ni = 0; ni < 4; ++ni) {
          const int f = ni * 16 + lcol;
          const f32x2 cs = cstab[t * 64 + f];
          const float a1 = acc[mi][ni][j];
          const float a2 = acc[mi][ni + 4][j];
          store_c(C + (size_t)r * N + n0 + f,      (a1 * cs.x - a2 * cs.y) * qsc);
          store_c(C + (size_t)r * N + n0 + f + 64, (a2 * cs.x + a1 * cs.y) * qsc);
        }
      }
  } else if (VT) {
    // v third: store transposed into vt[(b*16+h)*128 + d][t] (skip qkv store)
    const int h = (n0 - 2 * DMODEL) >> 7;
#pragma unroll
    for (int mi = 0; mi < 2; ++mi) {
      const int r0 = m0 + wm + mi * 16 + lrow * 4;
      const int b = r0 >> 11, t0 = r0 & (TSEQ - 1);
#pragma unroll
      for (int ni = 0; ni < 8; ++ni) {
        const int d = ni * 16 + lcol;
        s16x4 v4;
#pragma unroll
        for (int j = 0; j < 4; ++j) v4[j] = (short)bfbits(acc[mi][ni][j]);
        *reinterpret_cast<s16x4*>(
            vt + (size_t)((b * NHEAD + h) * DHEAD + d) * TSEQ + t0) = v4;
      }
    }
  } else {
#pragma unroll
    for (int mi = 0; mi < 2; ++mi)
#pragma unroll
      for (int ni = 0; ni < 8; ++ni)
#pragma unroll
        for (int j = 0; j < 4; ++j) {
          int r = m0 + wm + mi * 16 + lrow * 4 + j;
          int c = n0 + ni * 16 + lcol;
          store_c(C + (size_t)r * N + c, acc[mi][ni][j]);
        }
  }
}

// ---------------------------------------------------------------- flash attention (causal) — r12/r13 verified
// 8 waves x 16 q-rows; KV staged once per block, double-buffered, XOR-swizzled.
// Complementary CU-pair balance: x = b ? 15-raw : raw.
__global__ __launch_bounds__(512, 4) void flash_attn(const unsigned short* __restrict__ qkv,
                                                     const unsigned short* __restrict__ vt,
                                                     unsigned short* __restrict__ out) {
  __shared__ unsigned short kb[2][64 * 128];
  __shared__ unsigned short vb[2][128 * 64];
  __shared__ unsigned short plds[8][16 * 64];

  const int tid  = threadIdx.x;
  const int wave = tid >> 6, lane = tid & 63;
  const int lrow = lane >> 4, lcol = lane & 15;
  const int h = blockIdx.y, b = blockIdx.z;
  const int x = b ? (15 - (int)blockIdx.x) : (int)blockIdx.x;
  const int q0b = x * 128;
  const int q0w = q0b + wave * 16;
  const size_t qkbase = (size_t)b * TSEQ * (3 * DMODEL);
  const unsigned short* kptr = qkv + qkbase + DMODEL + h * DHEAD;
  const unsigned short* vptr = vt + (size_t)((b * NHEAD + h) * DHEAD) * TSEQ;

  bf16x8 qf[4];
#pragma unroll
  for (int kk = 0; kk < 4; ++kk)
    qf[kk] = *reinterpret_cast<const bf16x8*>(
        qkv + qkbase + (size_t)(q0w + lcol) * (3 * DMODEL) + h * DHEAD + kk * 32 + lrow * 8);

  f32x4 o[8] = {};
  float m = -1.0e30f, l = 0.f;

  const int nsteps = 2 * x + 2;

#define STAGE_KV(bi, kv0s)                                                              \
  {                                                                                     \
    _Pragma("unroll")                                                                   \
    for (int c = 0; c < 2; ++c) {                                                       \
      int cc = c * 512 + tid;                                                           \
      int krow = cc >> 4, kchk = (cc & 15) ^ (krow & 7);                                \
      GLOAD_LDS16(kptr + (size_t)((kv0s) + krow) * (3 * DMODEL) + kchk * 8,             \
                  &kb[bi][cc * 8]);                                                     \
      int vrow = cc >> 3, vchk = (cc & 7) ^ (vrow & 7);                                 \
      GLOAD_LDS16(vptr + (size_t)vrow * TSEQ + (kv0s) + vchk * 8,                       \
                  &vb[bi][cc * 8]);                                                     \
    }                                                                                   \
  }

  STAGE_KV(0, 0);
  __syncthreads();

  int cur = 0;
  for (int s = 0; s < nsteps; ++s) {
    const int kv0 = s * 64;
    if (s + 1 < nsteps) STAGE_KV(cur ^ 1, kv0 + 64);

    if (kv0 <= q0w + 15) {
      const unsigned short* kbc = kb[cur];
      const unsigned short* vbc = vb[cur];

      f32x4 sc[4] = {};
      __builtin_amdgcn_s_setprio(1);
#pragma unroll
      for (int n = 0; n < 4; ++n) {
        const int r = n * 16 + lcol;
#pragma unroll
        for (int kk = 0; kk < 4; ++kk) {
          bf16x8 kf = *reinterpret_cast<const bf16x8*>(
              &kbc[r * 128 + (((kk * 4 + lrow) ^ (lcol & 7)) << 3)]);
          sc[n] = __builtin_amdgcn_mfma_f32_16x16x32_bf16(kf, qf[kk], sc[n], 0, 0, 0);
        }
      }
      __builtin_amdgcn_s_setprio(0);

      const bool diag = (kv0 + 63 > q0w);
      const int qi = q0w + lcol;
      float sv[16];
#pragma unroll
      for (int n = 0; n < 4; ++n)
#pragma unroll
        for (int j = 0; j < 4; ++j) {
          float v = sc[n][j];
          if (diag && (kv0 + n * 16 + lrow * 4 + j) > qi) v = -1.0e30f;
          sv[n * 4 + j] = v;
        }
      float t8[8];
#pragma unroll
      for (int j = 0; j < 8; ++j) t8[j] = fmaxf(sv[j], sv[j + 8]);
#pragma unroll
      for (int j = 0; j < 4; ++j) t8[j] = fmaxf(t8[j], t8[j + 4]);
      float pm = fmaxf(fmaxf(t8[0], t8[1]), fmaxf(t8[2], t8[3]));
      pm = fmaxf(pm, __shfl_xor(pm, 16));
      pm = fmaxf(pm, __shfl_xor(pm, 32));

      if (__any(pm > m + 11.5f)) {   // defer-max (T13, THR = 8 nats = 11.5 log2)
        const float mn  = fmaxf(m, pm);
        const float fsc = EXP2(m - mn);
        m = mn;
        l *= fsc;
#pragma unroll
        for (int c = 0; c < 8; ++c) o[c] *= fsc;
      }

#pragma unroll
      for (int i = 0; i < 16; ++i) sv[i] = EXP2(sv[i] - m);
      float a8[8];
#pragma unroll
      for (int j = 0; j < 8; ++j) a8[j] = sv[j] + sv[j + 8];
#pragma unroll
      for (int j = 0; j < 4; ++j) a8[j] += a8[j + 4];
      float rs = (a8[0] + a8[1]) + (a8[2] + a8[3]);
      rs += __shfl_xor(rs, 16);
      rs += __shfl_xor(rs, 32);
      l += rs;

      char* pw = reinterpret_cast<char*>(&plds[wave][0]);
#pragma unroll
      for (int n = 0; n < 4; ++n)
#pragma unroll
        for (int j = 0; j < 4; j += 2) {
          int boff = (lcol << 7) + ((((n << 1) + (lrow >> 1)) ^ (lcol & 7)) << 4) +
                     ((lrow & 1) << 3) + (j << 1);
          *reinterpret_cast<unsigned int*>(pw + boff) = pack2(sv[n * 4 + j], sv[n * 4 + j + 1]);
        }
      asm volatile("s_waitcnt lgkmcnt(0)" ::: "memory");

      bf16x8 pf0 = *reinterpret_cast<const bf16x8*>(
          pw + (lcol << 7) + ((lrow ^ (lcol & 7)) << 4));
      bf16x8 pf1 = *reinterpret_cast<const bf16x8*>(
          pw + (lcol << 7) + (((4 + lrow) ^ (lcol & 7)) << 4));

      __builtin_amdgcn_s_setprio(1);
#pragma unroll
      for (int c = 0; c < 8; ++c) {
        const int d = c * 16 + lcol;
        bf16x8 vf0 = *reinterpret_cast<const bf16x8*>(
            &vbc[d * 64 + ((lrow ^ (lcol & 7)) << 3)]);
        o[c] = __builtin_amdgcn_mfma_f32_16x16x32_bf16(vf0, pf0, o[c], 0, 0, 0);
        bf16x8 vf1 = *reinterpret_cast<const bf16x8*>(
            &vbc[d * 64 + (((4 + lrow) ^ (lcol & 7)) << 3)]);
        o[c] = __builtin_amdgcn_mfma_f32_16x16x32_bf16(vf1, pf1, o[c], 0, 0, 0);
      }
      __builtin_amdgcn_s_setprio(0);
    }

    __syncthreads();
    cur ^= 1;
  }

  const float rl = 1.0f / l;
  const int trow = q0w + lcol;
#pragma unroll
  for (int c = 0; c < 8; ++c) {
    s16x4 st;
#pragma unroll
    for (int j = 0; j < 4; ++j) st[j] = (short)bfbits(o[c][j] * rl);
    *reinterpret_cast<s16x4*>(
        out + (size_t)(b * TSEQ + trow) * DMODEL + h * DHEAD + c * 16 + lrow * 4) = st;
  }
#undef STAGE_KV
}

// ---------------------------------------------------------------- launcher
extern "C" void kernel_launch(void* const* d_in, const int* in_sizes, int n_in,
                              void* d_out, int out_size, void* d_ws, size_t ws_size,
                              hipStream_t stream) {
  const float* x     = (const float*)d_in[0];
  const float* w_qkv = (const float*)d_in[1];
  const float* w_op  = (const float*)d_in[2];
  float* out = (float*)d_out;

  const size_t SZ_XB  = (size_t)4096 * 2048 * 2;
  const size_t SZ_WQ  = (size_t)6144 * 2048 * 2;
  const size_t SZ_WO  = (size_t)2048 * 2048 * 2;
  const size_t SZ_QKV = (size_t)4096 * 6144 * 2;
  const size_t SZ_VT  = (size_t)32 * 128 * 2048 * 2;
  const size_t SZ_AO  = (size_t)4096 * 2048 * 2;
  const size_t SZ_TAB = (size_t)2048 * 64 * 8;
  const size_t NEEDED = SZ_XB + SZ_WQ + SZ_WO + SZ_QKV + SZ_VT + SZ_AO + SZ_TAB;
  if (ws_size < NEEDED) return;

  char* p = (char*)d_ws;
  unsigned short* xb   = (unsigned short*)p; p += SZ_XB;
  unsigned short* wqb  = (unsigned short*)p; p += SZ_WQ;
  unsigned short* wob  = (unsigned short*)p; p += SZ_WO;
  unsigned short* qkv  = (unsigned short*)p; p += SZ_QKV;
  unsigned short* vt   = (unsigned short*)p; p += SZ_VT;
  unsigned short* ao   = (unsigned short*)p; p += SZ_AO;
  f32x2* cstab = (f32x2*)p; p += SZ_TAB;

  cast_all<<<dim3(2048), dim3(256), 0, stream>>>(x, w_qkv, w_op, xb, wqb, wob);
  rope_tables<<<dim3(512), dim3(256), 0, stream>>>(cstab);

  // qkv = x @ w_qkv^T with fused RoPE (+ q scale * log2e) on q,k thirds and
  // fused transposed V store (v third -> vt directly)
  gemm_bt<unsigned short, true, true><<<dim3(32, 48), dim3(256), 0, stream>>>(
      xb, wqb, qkv, 4096, 6144, 2048, cstab, vt);
  // causal flash attention (512 blocks, all-resident, CU-pair balanced)
  flash_attn<<<dim3(16, 16, 2), dim3(512), 0, stream>>>(qkv, vt, ao);
  // out = attn_out @ w_op^T
  gemm_bt<float, false, false><<<dim3(32, 16), dim3(256), 0, stream>>>(
      ao, wob, out, 4096, 2048, 2048, nullptr, nullptr);
}

// Round 16
// 249.863 us; speedup vs baseline: 1.0531x; 1.0196x over previous
//
#include <hip/hip_runtime.h>
#include <hip/hip_bf16.h>
#include <cstdint>

#define NHEAD 16
#define DHEAD 128
#define DMODEL 2048
#define TSEQ 2048
#define BATCH 2

using bf16 = __hip_bfloat16;
typedef __attribute__((ext_vector_type(4))) float  f32x4;
typedef __attribute__((ext_vector_type(2))) float  f32x2;
typedef __attribute__((ext_vector_type(4))) float  float4_t;
typedef __attribute__((ext_vector_type(4))) short  s16x4;
typedef __bf16 bf16x8 __attribute__((ext_vector_type(8)));

#define GLOAD_LDS16(gptr, lptr)                                                        \
  __builtin_amdgcn_global_load_lds((const __attribute__((address_space(1))) void*)(gptr), \
                                   (__attribute__((address_space(3))) void*)(lptr), 16, 0, 0)

#if __has_builtin(__builtin_amdgcn_exp2f)
#define EXP2(x) __builtin_amdgcn_exp2f(x)
#else
#define EXP2(x) exp2f(x)
#endif

__device__ __forceinline__ float bf2f(bf16 v) { return __bfloat162float(v); }
__device__ __forceinline__ bf16  f2bf(float f) { return __float2bfloat16(f); }
__device__ __forceinline__ unsigned short bfbits(float f) {
  return __builtin_bit_cast(unsigned short, f2bf(f));
}
__device__ __forceinline__ unsigned int pack2(float a, float b) {
  return (unsigned int)bfbits(a) | ((unsigned int)bfbits(b) << 16);
}

// ---------------------------------------------------------------- fused cast fp32 -> bf16 (all three inputs)
#define N4_X  (4096 * 2048 / 4)
#define N4_WQ (6144 * 2048 / 4)
#define N4_WO (2048 * 2048 / 4)
__global__ void cast_all(const float* __restrict__ x, const float* __restrict__ wq,
                         const float* __restrict__ wo, unsigned short* __restrict__ xb,
                         unsigned short* __restrict__ wqb, unsigned short* __restrict__ wob) {
  const int total = N4_X + N4_WQ + N4_WO;
  int stride = gridDim.x * blockDim.x;
  for (int i = blockIdx.x * blockDim.x + threadIdx.x; i < total; i += stride) {
    const float* src;
    unsigned short* dst;
    int j;
    if (i < N4_X)            { src = x;  dst = xb;  j = i; }
    else if (i < N4_X + N4_WQ) { src = wq; dst = wqb; j = i - N4_X; }
    else                     { src = wo; dst = wob; j = i - N4_X - N4_WQ; }
    float4_t v = reinterpret_cast<const float4_t*>(src)[j];
    s16x4 r;
    r.x = (short)bfbits(v.x);
    r.y = (short)bfbits(v.y);
    r.z = (short)bfbits(v.z);
    r.w = (short)bfbits(v.w);
    reinterpret_cast<s16x4*>(dst)[j] = r;
  }
}

// ---------------------------------------------------------------- RoPE tables (fp32 packed, [T][64] of (cos,sin))
__global__ void rope_tables(f32x2* __restrict__ cstab) {
  int i = blockIdx.x * blockDim.x + threadIdx.x;
  if (i >= TSEQ * 64) return;
  int t = i >> 6, f = i & 63;
  float inv = __expf(-((2.0f * (float)f) / 128.0f) * logf(10000.0f));
  float ang = (float)t * inv;
  f32x2 cs;
  cs.x = cosf(ang);
  cs.y = sinf(ang);
  cstab[i] = cs;
}

// ---------------------------------------------------------------- C store helpers
__device__ __forceinline__ void store_c(float* p, float v) { *p = v; }
__device__ __forceinline__ void store_c(unsigned short* p, float v) { *p = bfbits(v); }

// ---------------------------------------------------------------- bf16 GEMM, C = A(MxK) * B(NxK)^T
// r13-verified core (BK=64, single-buffer staging, 128-B LDS rows, 8-chunk XOR
// swizzle, 16x16x32 MFMA, 0 bank conflicts) with waves re-partitioned to
// 64x64 tiles (2M x 2N): per ks, af[4]+bfr[4] = 8 ds_read for 16 MFMA
// (16 reads/K-tile vs r13's 20 — the GEMM is LDS-read-issue-bound).
// N-fragment interleave j = 2*ni + wn keeps RoPE pairs (j, j+4) in-lane.
// ROPE: rotary on q,k thirds (q pre-scaled by (1/sqrt(DH))*log2e).
// VT: v third stored transposed into vt[(b*16+h)*128+d][t].
template <typename CT, bool ROPE, bool VT>
__global__ __launch_bounds__(256, 2) void gemm_bt(const unsigned short* __restrict__ A,
                                                  const unsigned short* __restrict__ B,
                                                  CT* __restrict__ C, int M, int N, int K,
                                                  const f32x2* __restrict__ cstab,
                                                  unsigned short* __restrict__ vt) {
  __shared__ __align__(16) unsigned short As[128 * 64];   // 16 KB
  __shared__ __align__(16) unsigned short Bs[128 * 64];   // 16 KB
  const int tid  = threadIdx.x;
  const int wave = tid >> 6, lane = tid & 63;
  const int m0 = blockIdx.x * 128, n0 = blockIdx.y * 128;
  const int wm2 = wave >> 1, wn = wave & 1;   // 2M x 2N wave grid
  const int lrow = lane >> 4, lcol = lane & 15;
  f32x4 acc[4][4] = {};   // [M-frag mi][N-slot ni], col frag j = 2*ni + wn

  // fragment read: row R, k-half ks: chunk = (ks*4 + lrow) ^ (R & 7)
#define RD_FRAG(BASE, R, ks)                                                    \
  (*reinterpret_cast<const bf16x8*>(                                            \
      (const char*)(BASE) + (R) * 128 + (((((ks) << 2) + lrow) ^ ((R) & 7)) << 4)))

  for (int k0 = 0; k0 < K; k0 += 64) {
    // stage 128x64 of A and B: 1024 chunks each, 4/thread; linear dest, swizzled src
#pragma unroll
    for (int it = 0; it < 4; ++it) {
      int CC = it * 256 + tid;
      int R = CC >> 3, ch = CC & 7;
      int kg = (ch ^ (R & 7)) << 3;
      GLOAD_LDS16(A + (size_t)(m0 + R) * K + k0 + kg, (char*)As + CC * 16);
      GLOAD_LDS16(B + (size_t)(n0 + R) * K + k0 + kg, (char*)Bs + CC * 16);
    }
    __syncthreads();
#pragma unroll
    for (int ks = 0; ks < 2; ++ks) {
      bf16x8 af[4], bfr[4];
#pragma unroll
      for (int mi = 0; mi < 4; ++mi)
        af[mi] = RD_FRAG(As, wm2 * 64 + mi * 16 + lcol, ks);
#pragma unroll
      for (int ni = 0; ni < 4; ++ni)
        bfr[ni] = RD_FRAG(Bs, (2 * ni + wn) * 16 + lcol, ks);
#pragma unroll
      for (int mi = 0; mi < 4; ++mi)
#pragma unroll
        for (int ni = 0; ni < 4; ++ni)
          acc[mi][ni] = __builtin_amdgcn_mfma_f32_16x16x32_bf16(af[mi], bfr[ni], acc[mi][ni], 0, 0, 0);
    }
    __syncthreads();
  }
#undef RD_FRAG

  if (ROPE && n0 < 2 * DMODEL) {
    const float qsc = (n0 < DMODEL) ? 0.12751743f : 1.0f;   // 1/sqrt(128) * log2e for q
#pragma unroll
    for (int mi = 0; mi < 4; ++mi)
#pragma unroll
      for (int j = 0; j < 4; ++j) {
        const int r = m0 + wm2 * 64 + mi * 16 + lrow * 4 + j;
        const int t = r & (TSEQ - 1);
#pragma unroll
        for (int ni = 0; ni < 2; ++ni) {   // col frags j=2ni+wn (<4); partner j+4 = acc[mi][ni+2]
          const int f = (2 * ni + wn) * 16 + lcol;
          const f32x2 cs = cstab[t * 64 + f];
          const float a1 = acc[mi][ni][j];
          const float a2 = acc[mi][ni + 2][j];
          store_c(C + (size_t)r * N + n0 + f,      (a1 * cs.x - a2 * cs.y) * qsc);
          store_c(C + (size_t)r * N + n0 + f + 64, (a2 * cs.x + a1 * cs.y) * qsc);
        }
      }
  } else if (VT) {
    // v third: store transposed into vt[(b*16+h)*128 + d][t] (skip qkv store)
    const int h = (n0 - 2 * DMODEL) >> 7;
#pragma unroll
    for (int mi = 0; mi < 4; ++mi) {
      const int r0 = m0 + wm2 * 64 + mi * 16 + lrow * 4;
      const int b = r0 >> 11, t0 = r0 & (TSEQ - 1);
#pragma unroll
      for (int ni = 0; ni < 4; ++ni) {
        const int d = (2 * ni + wn) * 16 + lcol;
        s16x4 v4;
#pragma unroll
        for (int j = 0; j < 4; ++j) v4[j] = (short)bfbits(acc[mi][ni][j]);
        *reinterpret_cast<s16x4*>(
            vt + (size_t)((b * NHEAD + h) * DHEAD + d) * TSEQ + t0) = v4;
      }
    }
  } else {
#pragma unroll
    for (int mi = 0; mi < 4; ++mi)
#pragma unroll
      for (int ni = 0; ni < 4; ++ni)
#pragma unroll
        for (int j = 0; j < 4; ++j) {
          int r = m0 + wm2 * 64 + mi * 16 + lrow * 4 + j;
          int c = n0 + (2 * ni + wn) * 16 + lcol;
          store_c(C + (size_t)r * N + c, acc[mi][ni][j]);
        }
  }
}

// ---------------------------------------------------------------- flash attention (causal) — r12/r13 verified
// 8 waves x 16 q-rows; KV staged once per block, double-buffered, XOR-swizzled.
// Complementary CU-pair balance: x = b ? 15-raw : raw.
__global__ __launch_bounds__(512, 4) void flash_attn(const unsigned short* __restrict__ qkv,
                                                     const unsigned short* __restrict__ vt,
                                                     unsigned short* __restrict__ out) {
  __shared__ unsigned short kb[2][64 * 128];
  __shared__ unsigned short vb[2][128 * 64];
  __shared__ unsigned short plds[8][16 * 64];

  const int tid  = threadIdx.x;
  const int wave = tid >> 6, lane = tid & 63;
  const int lrow = lane >> 4, lcol = lane & 15;
  const int h = blockIdx.y, b = blockIdx.z;
  const int x = b ? (15 - (int)blockIdx.x) : (int)blockIdx.x;
  const int q0b = x * 128;
  const int q0w = q0b + wave * 16;
  const size_t qkbase = (size_t)b * TSEQ * (3 * DMODEL);
  const unsigned short* kptr = qkv + qkbase + DMODEL + h * DHEAD;
  const unsigned short* vptr = vt + (size_t)((b * NHEAD + h) * DHEAD) * TSEQ;

  bf16x8 qf[4];
#pragma unroll
  for (int kk = 0; kk < 4; ++kk)
    qf[kk] = *reinterpret_cast<const bf16x8*>(
        qkv + qkbase + (size_t)(q0w + lcol) * (3 * DMODEL) + h * DHEAD + kk * 32 + lrow * 8);

  f32x4 o[8] = {};
  float m = -1.0e30f, l = 0.f;

  const int nsteps = 2 * x + 2;

#define STAGE_KV(bi, kv0s)                                                              \
  {                                                                                     \
    _Pragma("unroll")                                                                   \
    for (int c = 0; c < 2; ++c) {                                                       \
      int cc = c * 512 + tid;                                                           \
      int krow = cc >> 4, kchk = (cc & 15) ^ (krow & 7);                                \
      GLOAD_LDS16(kptr + (size_t)((kv0s) + krow) * (3 * DMODEL) + kchk * 8,             \
                  &kb[bi][cc * 8]);                                                     \
      int vrow = cc >> 3, vchk = (cc & 7) ^ (vrow & 7);                                 \
      GLOAD_LDS16(vptr + (size_t)vrow * TSEQ + (kv0s) + vchk * 8,                       \
                  &vb[bi][cc * 8]);                                                     \
    }                                                                                   \
  }

  STAGE_KV(0, 0);
  __syncthreads();

  int cur = 0;
  for (int s = 0; s < nsteps; ++s) {
    const int kv0 = s * 64;
    if (s + 1 < nsteps) STAGE_KV(cur ^ 1, kv0 + 64);

    if (kv0 <= q0w + 15) {
      const unsigned short* kbc = kb[cur];
      const unsigned short* vbc = vb[cur];

      f32x4 sc[4] = {};
      __builtin_amdgcn_s_setprio(1);
#pragma unroll
      for (int n = 0; n < 4; ++n) {
        const int r = n * 16 + lcol;
#pragma unroll
        for (int kk = 0; kk < 4; ++kk) {
          bf16x8 kf = *reinterpret_cast<const bf16x8*>(
              &kbc[r * 128 + (((kk * 4 + lrow) ^ (lcol & 7)) << 3)]);
          sc[n] = __builtin_amdgcn_mfma_f32_16x16x32_bf16(kf, qf[kk], sc[n], 0, 0, 0);
        }
      }
      __builtin_amdgcn_s_setprio(0);

      const bool diag = (kv0 + 63 > q0w);
      const int qi = q0w + lcol;
      float sv[16];
#pragma unroll
      for (int n = 0; n < 4; ++n)
#pragma unroll
        for (int j = 0; j < 4; ++j) {
          float v = sc[n][j];
          if (diag && (kv0 + n * 16 + lrow * 4 + j) > qi) v = -1.0e30f;
          sv[n * 4 + j] = v;
        }
      float t8[8];
#pragma unroll
      for (int j = 0; j < 8; ++j) t8[j] = fmaxf(sv[j], sv[j + 8]);
#pragma unroll
      for (int j = 0; j < 4; ++j) t8[j] = fmaxf(t8[j], t8[j + 4]);
      float pm = fmaxf(fmaxf(t8[0], t8[1]), fmaxf(t8[2], t8[3]));
      pm = fmaxf(pm, __shfl_xor(pm, 16));
      pm = fmaxf(pm, __shfl_xor(pm, 32));

      if (__any(pm > m + 11.5f)) {   // defer-max (T13, THR = 8 nats = 11.5 log2)
        const float mn  = fmaxf(m, pm);
        const float fsc = EXP2(m - mn);
        m = mn;
        l *= fsc;
#pragma unroll
        for (int c = 0; c < 8; ++c) o[c] *= fsc;
      }

#pragma unroll
      for (int i = 0; i < 16; ++i) sv[i] = EXP2(sv[i] - m);
      float a8[8];
#pragma unroll
      for (int j = 0; j < 8; ++j) a8[j] = sv[j] + sv[j + 8];
#pragma unroll
      for (int j = 0; j < 4; ++j) a8[j] += a8[j + 4];
      float rs = (a8[0] + a8[1]) + (a8[2] + a8[3]);
      rs += __shfl_xor(rs, 16);
      rs += __shfl_xor(rs, 32);
      l += rs;

      char* pw = reinterpret_cast<char*>(&plds[wave][0]);
#pragma unroll
      for (int n = 0; n < 4; ++n)
#pragma unroll
        for (int j = 0; j < 4; j += 2) {
          int boff = (lcol << 7) + ((((n << 1) + (lrow >> 1)) ^ (lcol & 7)) << 4) +
                     ((lrow & 1) << 3) + (j << 1);
          *reinterpret_cast<unsigned int*>(pw + boff) = pack2(sv[n * 4 + j], sv[n * 4 + j + 1]);
        }
      asm volatile("s_waitcnt lgkmcnt(0)" ::: "memory");

      bf16x8 pf0 = *reinterpret_cast<const bf16x8*>(
          pw + (lcol << 7) + ((lrow ^ (lcol & 7)) << 4));
      bf16x8 pf1 = *reinterpret_cast<const bf16x8*>(
          pw + (lcol << 7) + (((4 + lrow) ^ (lcol & 7)) << 4));

      __builtin_amdgcn_s_setprio(1);
#pragma unroll
      for (int c = 0; c < 8; ++c) {
        const int d = c * 16 + lcol;
        bf16x8 vf0 = *reinterpret_cast<const bf16x8*>(
            &vbc[d * 64 + ((lrow ^ (lcol & 7)) << 3)]);
        o[c] = __builtin_amdgcn_mfma_f32_16x16x32_bf16(vf0, pf0, o[c], 0, 0, 0);
        bf16x8 vf1 = *reinterpret_cast<const bf16x8*>(
            &vbc[d * 64 + (((4 + lrow) ^ (lcol & 7)) << 3)]);
        o[c] = __builtin_amdgcn_mfma_f32_16x16x32_bf16(vf1, pf1, o[c], 0, 0, 0);
      }
      __builtin_amdgcn_s_setprio(0);
    }

    __syncthreads();
    cur ^= 1;
  }

  const float rl = 1.0f / l;
  const int trow = q0w + lcol;
#pragma unroll
  for (int c = 0; c < 8; ++c) {
    s16x4 st;
#pragma unroll
    for (int j = 0; j < 4; ++j) st[j] = (short)bfbits(o[c][j] * rl);
    *reinterpret_cast<s16x4*>(
        out + (size_t)(b * TSEQ + trow) * DMODEL + h * DHEAD + c * 16 + lrow * 4) = st;
  }
#undef STAGE_KV
}

// ---------------------------------------------------------------- launcher
extern "C" void kernel_launch(void* const* d_in, const int* in_sizes, int n_in,
                              void* d_out, int out_size, void* d_ws, size_t ws_size,
                              hipStream_t stream) {
  const float* x     = (const float*)d_in[0];
  const float* w_qkv = (const float*)d_in[1];
  const float* w_op  = (const float*)d_in[2];
  float* out = (float*)d_out;

  const size_t SZ_XB  = (size_t)4096 * 2048 * 2;
  const size_t SZ_WQ  = (size_t)6144 * 2048 * 2;
  const size_t SZ_WO  = (size_t)2048 * 2048 * 2;
  const size_t SZ_QKV = (size_t)4096 * 6144 * 2;
  const size_t SZ_VT  = (size_t)32 * 128 * 2048 * 2;
  const size_t SZ_AO  = (size_t)4096 * 2048 * 2;
  const size_t SZ_TAB = (size_t)2048 * 64 * 8;
  const size_t NEEDED = SZ_XB + SZ_WQ + SZ_WO + SZ_QKV + SZ_VT + SZ_AO + SZ_TAB;
  if (ws_size < NEEDED) return;

  char* p = (char*)d_ws;
  unsigned short* xb   = (unsigned short*)p; p += SZ_XB;
  unsigned short* wqb  = (unsigned short*)p; p += SZ_WQ;
  unsigned short* wob  = (unsigned short*)p; p += SZ_WO;
  unsigned short* qkv  = (unsigned short*)p; p += SZ_QKV;
  unsigned short* vt   = (unsigned short*)p; p += SZ_VT;
  unsigned short* ao   = (unsigned short*)p; p += SZ_AO;
  f32x2* cstab = (f32x2*)p; p += SZ_TAB;

  cast_all<<<dim3(2048), dim3(256), 0, stream>>>(x, w_qkv, w_op, xb, wqb, wob);
  rope_tables<<<dim3(512), dim3(256), 0, stream>>>(cstab);

  // qkv = x @ w_qkv^T with fused RoPE (+ q scale * log2e) on q,k thirds and
  // fused transposed V store (v third -> vt directly)
  gemm_bt<unsigned short, true, true><<<dim3(32, 48), dim3(256), 0, stream>>>(
      xb, wqb, qkv, 4096, 6144, 2048, cstab, vt);
  // causal flash attention (512 blocks, all-resident, CU-pair balanced)
  flash_attn<<<dim3(16, 16, 2), dim3(512), 0, stream>>>(qkv, vt, ao);
  // out = attn_out @ w_op^T
  gemm_bt<float, false, false><<<dim3(32, 16), dim3(256), 0, stream>>>(
      ao, wob, out, 4096, 2048, 2048, nullptr, nullptr);
}

// Round 17
// 246.165 us; speedup vs baseline: 1.0689x; 1.0150x over previous
//
#include <hip/hip_runtime.h>
#include <hip/hip_bf16.h>
#include <cstdint>

#define NHEAD 16
#define DHEAD 128
#define DMODEL 2048
#define TSEQ 2048
#define BATCH 2

using bf16 = __hip_bfloat16;
typedef __attribute__((ext_vector_type(4))) float  f32x4;
typedef __attribute__((ext_vector_type(2))) float  f32x2;
typedef __attribute__((ext_vector_type(4))) float  float4_t;
typedef __attribute__((ext_vector_type(4))) short  s16x4;
typedef __bf16 bf16x8 __attribute__((ext_vector_type(8)));

#define GLOAD_LDS16(gptr, lptr)                                                        \
  __builtin_amdgcn_global_load_lds((const __attribute__((address_space(1))) void*)(gptr), \
                                   (__attribute__((address_space(3))) void*)(lptr), 16, 0, 0)

#if __has_builtin(__builtin_amdgcn_exp2f)
#define EXP2(x) __builtin_amdgcn_exp2f(x)
#else
#define EXP2(x) exp2f(x)
#endif

__device__ __forceinline__ float bf2f(bf16 v) { return __bfloat162float(v); }
__device__ __forceinline__ bf16  f2bf(float f) { return __float2bfloat16(f); }
__device__ __forceinline__ unsigned short bfbits(float f) {
  return __builtin_bit_cast(unsigned short, f2bf(f));
}
__device__ __forceinline__ unsigned int pack2(float a, float b) {
  return (unsigned int)bfbits(a) | ((unsigned int)bfbits(b) << 16);
}

// ---------------------------------------------------------------- fused prep: cast fp32->bf16 (3 inputs) + RoPE tables
#define N4_X   (4096 * 2048 / 4)
#define N4_WQ  (6144 * 2048 / 4)
#define N4_WO  (2048 * 2048 / 4)
#define N_TAB  (TSEQ * 64)
__global__ void prep_all(const float* __restrict__ x, const float* __restrict__ wq,
                         const float* __restrict__ wo, unsigned short* __restrict__ xb,
                         unsigned short* __restrict__ wqb, unsigned short* __restrict__ wob,
                         f32x2* __restrict__ cstab) {
  const int total = N4_X + N4_WQ + N4_WO + N_TAB;
  int stride = gridDim.x * blockDim.x;
  for (int i = blockIdx.x * blockDim.x + threadIdx.x; i < total; i += stride) {
    if (i < N4_X + N4_WQ + N4_WO) {
      const float* src;
      unsigned short* dst;
      int j;
      if (i < N4_X)              { src = x;  dst = xb;  j = i; }
      else if (i < N4_X + N4_WQ) { src = wq; dst = wqb; j = i - N4_X; }
      else                       { src = wo; dst = wob; j = i - N4_X - N4_WQ; }
      float4_t v = reinterpret_cast<const float4_t*>(src)[j];
      s16x4 r;
      r.x = (short)bfbits(v.x);
      r.y = (short)bfbits(v.y);
      r.z = (short)bfbits(v.z);
      r.w = (short)bfbits(v.w);
      reinterpret_cast<s16x4*>(dst)[j] = r;
    } else {
      int j = i - (N4_X + N4_WQ + N4_WO);
      int t = j >> 6, f = j & 63;
      float inv = __expf(-((2.0f * (float)f) / 128.0f) * logf(10000.0f));
      float ang = (float)t * inv;
      f32x2 cs;
      cs.x = cosf(ang);
      cs.y = sinf(ang);
      cstab[j] = cs;
    }
  }
}

// ---------------------------------------------------------------- C store helpers
__device__ __forceinline__ void store_c(float* p, float v) { *p = v; }
__device__ __forceinline__ void store_c(unsigned short* p, float v) { *p = bfbits(v); }

// ---------------------------------------------------------------- bf16 GEMM, C = A(MxK) * B(NxK)^T
// r16-verified core (BK=64, single-buffer staging, 128-B LDS rows, 8-chunk XOR
// swizzle, 16x16x32 MFMA, 64x64 wave tiles (2Mx2N), 0 bank conflicts) with
// __launch_bounds__(256, 4): VGPR=60 and LDS=32KB allow 4 blocks/CU — the
// per-block barrier-drain stall is covered by co-resident blocks (m114 overlap).
// N-fragment interleave j = 2*ni + wn keeps RoPE pairs (j, j+4) in-lane.
// ROPE: rotary on q,k thirds (q pre-scaled by (1/sqrt(DH))*log2e).
// VT: v third stored transposed into vt[(b*16+h)*128+d][t].
template <typename CT, bool ROPE, bool VT>
__global__ __launch_bounds__(256, 4) void gemm_bt(const unsigned short* __restrict__ A,
                                                  const unsigned short* __restrict__ B,
                                                  CT* __restrict__ C, int M, int N, int K,
                                                  const f32x2* __restrict__ cstab,
                                                  unsigned short* __restrict__ vt) {
  __shared__ __align__(16) unsigned short As[128 * 64];   // 16 KB
  __shared__ __align__(16) unsigned short Bs[128 * 64];   // 16 KB
  const int tid  = threadIdx.x;
  const int wave = tid >> 6, lane = tid & 63;
  const int m0 = blockIdx.x * 128, n0 = blockIdx.y * 128;
  const int wm2 = wave >> 1, wn = wave & 1;   // 2M x 2N wave grid
  const int lrow = lane >> 4, lcol = lane & 15;
  f32x4 acc[4][4] = {};   // [M-frag mi][N-slot ni], col frag j = 2*ni + wn

  // fragment read: row R, k-half ks: chunk = (ks*4 + lrow) ^ (R & 7)
#define RD_FRAG(BASE, R, ks)                                                    \
  (*reinterpret_cast<const bf16x8*>(                                            \
      (const char*)(BASE) + (R) * 128 + (((((ks) << 2) + lrow) ^ ((R) & 7)) << 4)))

  for (int k0 = 0; k0 < K; k0 += 64) {
    // stage 128x64 of A and B: 1024 chunks each, 4/thread; linear dest, swizzled src
#pragma unroll
    for (int it = 0; it < 4; ++it) {
      int CC = it * 256 + tid;
      int R = CC >> 3, ch = CC & 7;
      int kg = (ch ^ (R & 7)) << 3;
      GLOAD_LDS16(A + (size_t)(m0 + R) * K + k0 + kg, (char*)As + CC * 16);
      GLOAD_LDS16(B + (size_t)(n0 + R) * K + k0 + kg, (char*)Bs + CC * 16);
    }
    __syncthreads();
#pragma unroll
    for (int ks = 0; ks < 2; ++ks) {
      bf16x8 af[4], bfr[4];
#pragma unroll
      for (int mi = 0; mi < 4; ++mi)
        af[mi] = RD_FRAG(As, wm2 * 64 + mi * 16 + lcol, ks);
#pragma unroll
      for (int ni = 0; ni < 4; ++ni)
        bfr[ni] = RD_FRAG(Bs, (2 * ni + wn) * 16 + lcol, ks);
#pragma unroll
      for (int mi = 0; mi < 4; ++mi)
#pragma unroll
        for (int ni = 0; ni < 4; ++ni)
          acc[mi][ni] = __builtin_amdgcn_mfma_f32_16x16x32_bf16(af[mi], bfr[ni], acc[mi][ni], 0, 0, 0);
    }
    __syncthreads();
  }
#undef RD_FRAG

  if (ROPE && n0 < 2 * DMODEL) {
    const float qsc = (n0 < DMODEL) ? 0.12751743f : 1.0f;   // 1/sqrt(128) * log2e for q
#pragma unroll
    for (int mi = 0; mi < 4; ++mi)
#pragma unroll
      for (int j = 0; j < 4; ++j) {
        const int r = m0 + wm2 * 64 + mi * 16 + lrow * 4 + j;
        const int t = r & (TSEQ - 1);
#pragma unroll
        for (int ni = 0; ni < 2; ++ni) {   // col frags j=2ni+wn (<4); partner j+4 = acc[mi][ni+2]
          const int f = (2 * ni + wn) * 16 + lcol;
          const f32x2 cs = cstab[t * 64 + f];
          const float a1 = acc[mi][ni][j];
          const float a2 = acc[mi][ni + 2][j];
          store_c(C + (size_t)r * N + n0 + f,      (a1 * cs.x - a2 * cs.y) * qsc);
          store_c(C + (size_t)r * N + n0 + f + 64, (a2 * cs.x + a1 * cs.y) * qsc);
        }
      }
  } else if (VT) {
    // v third: store transposed into vt[(b*16+h)*128 + d][t] (skip qkv store)
    const int h = (n0 - 2 * DMODEL) >> 7;
#pragma unroll
    for (int mi = 0; mi < 4; ++mi) {
      const int r0 = m0 + wm2 * 64 + mi * 16 + lrow * 4;
      const int b = r0 >> 11, t0 = r0 & (TSEQ - 1);
#pragma unroll
      for (int ni = 0; ni < 4; ++ni) {
        const int d = (2 * ni + wn) * 16 + lcol;
        s16x4 v4;
#pragma unroll
        for (int j = 0; j < 4; ++j) v4[j] = (short)bfbits(acc[mi][ni][j]);
        *reinterpret_cast<s16x4*>(
            vt + (size_t)((b * NHEAD + h) * DHEAD + d) * TSEQ + t0) = v4;
      }
    }
  } else {
#pragma unroll
    for (int mi = 0; mi < 4; ++mi)
#pragma unroll
      for (int ni = 0; ni < 4; ++ni)
#pragma unroll
        for (int j = 0; j < 4; ++j) {
          int r = m0 + wm2 * 64 + mi * 16 + lrow * 4 + j;
          int c = n0 + (2 * ni + wn) * 16 + lcol;
          store_c(C + (size_t)r * N + c, acc[mi][ni][j]);
        }
  }
}

// ---------------------------------------------------------------- flash attention (causal) — r12/r13 verified
// 8 waves x 16 q-rows; KV staged once per block, double-buffered, XOR-swizzled.
// Complementary CU-pair balance: x = b ? 15-raw : raw.
__global__ __launch_bounds__(512, 4) void flash_attn(const unsigned short* __restrict__ qkv,
                                                     const unsigned short* __restrict__ vt,
                                                     unsigned short* __restrict__ out) {
  __shared__ unsigned short kb[2][64 * 128];
  __shared__ unsigned short vb[2][128 * 64];
  __shared__ unsigned short plds[8][16 * 64];

  const int tid  = threadIdx.x;
  const int wave = tid >> 6, lane = tid & 63;
  const int lrow = lane >> 4, lcol = lane & 15;
  const int h = blockIdx.y, b = blockIdx.z;
  const int x = b ? (15 - (int)blockIdx.x) : (int)blockIdx.x;
  const int q0b = x * 128;
  const int q0w = q0b + wave * 16;
  const size_t qkbase = (size_t)b * TSEQ * (3 * DMODEL);
  const unsigned short* kptr = qkv + qkbase + DMODEL + h * DHEAD;
  const unsigned short* vptr = vt + (size_t)((b * NHEAD + h) * DHEAD) * TSEQ;

  bf16x8 qf[4];
#pragma unroll
  for (int kk = 0; kk < 4; ++kk)
    qf[kk] = *reinterpret_cast<const bf16x8*>(
        qkv + qkbase + (size_t)(q0w + lcol) * (3 * DMODEL) + h * DHEAD + kk * 32 + lrow * 8);

  f32x4 o[8] = {};
  float m = -1.0e30f, l = 0.f;

  const int nsteps = 2 * x + 2;

#define STAGE_KV(bi, kv0s)                                                              \
  {                                                                                     \
    _Pragma("unroll")                                                                   \
    for (int c = 0; c < 2; ++c) {                                                       \
      int cc = c * 512 + tid;                                                           \
      int krow = cc >> 4, kchk = (cc & 15) ^ (krow & 7);                                \
      GLOAD_LDS16(kptr + (size_t)((kv0s) + krow) * (3 * DMODEL) + kchk * 8,             \
                  &kb[bi][cc * 8]);                                                     \
      int vrow = cc >> 3, vchk = (cc & 7) ^ (vrow & 7);                                 \
      GLOAD_LDS16(vptr + (size_t)vrow * TSEQ + (kv0s) + vchk * 8,                       \
                  &vb[bi][cc * 8]);                                                     \
    }                                                                                   \
  }

  STAGE_KV(0, 0);
  __syncthreads();

  int cur = 0;
  for (int s = 0; s < nsteps; ++s) {
    const int kv0 = s * 64;
    if (s + 1 < nsteps) STAGE_KV(cur ^ 1, kv0 + 64);

    if (kv0 <= q0w + 15) {
      const unsigned short* kbc = kb[cur];
      const unsigned short* vbc = vb[cur];

      f32x4 sc[4] = {};
      __builtin_amdgcn_s_setprio(1);
#pragma unroll
      for (int n = 0; n < 4; ++n) {
        const int r = n * 16 + lcol;
#pragma unroll
        for (int kk = 0; kk < 4; ++kk) {
          bf16x8 kf = *reinterpret_cast<const bf16x8*>(
              &kbc[r * 128 + (((kk * 4 + lrow) ^ (lcol & 7)) << 3)]);
          sc[n] = __builtin_amdgcn_mfma_f32_16x16x32_bf16(kf, qf[kk], sc[n], 0, 0, 0);
        }
      }
      __builtin_amdgcn_s_setprio(0);

      const bool diag = (kv0 + 63 > q0w);
      const int qi = q0w + lcol;
      float sv[16];
#pragma unroll
      for (int n = 0; n < 4; ++n)
#pragma unroll
        for (int j = 0; j < 4; ++j) {
          float v = sc[n][j];
          if (diag && (kv0 + n * 16 + lrow * 4 + j) > qi) v = -1.0e30f;
          sv[n * 4 + j] = v;
        }
      float t8[8];
#pragma unroll
      for (int j = 0; j < 8; ++j) t8[j] = fmaxf(sv[j], sv[j + 8]);
#pragma unroll
      for (int j = 0; j < 4; ++j) t8[j] = fmaxf(t8[j], t8[j + 4]);
      float pm = fmaxf(fmaxf(t8[0], t8[1]), fmaxf(t8[2], t8[3]));
      pm = fmaxf(pm, __shfl_xor(pm, 16));
      pm = fmaxf(pm, __shfl_xor(pm, 32));

      if (__any(pm > m + 11.5f)) {   // defer-max (T13, THR = 8 nats = 11.5 log2)
        const float mn  = fmaxf(m, pm);
        const float fsc = EXP2(m - mn);
        m = mn;
        l *= fsc;
#pragma unroll
        for (int c = 0; c < 8; ++c) o[c] *= fsc;
      }

#pragma unroll
      for (int i = 0; i < 16; ++i) sv[i] = EXP2(sv[i] - m);
      float a8[8];
#pragma unroll
      for (int j = 0; j < 8; ++j) a8[j] = sv[j] + sv[j + 8];
#pragma unroll
      for (int j = 0; j < 4; ++j) a8[j] += a8[j + 4];
      float rs = (a8[0] + a8[1]) + (a8[2] + a8[3]);
      rs += __shfl_xor(rs, 16);
      rs += __shfl_xor(rs, 32);
      l += rs;

      char* pw = reinterpret_cast<char*>(&plds[wave][0]);
#pragma unroll
      for (int n = 0; n < 4; ++n)
#pragma unroll
        for (int j = 0; j < 4; j += 2) {
          int boff = (lcol << 7) + ((((n << 1) + (lrow >> 1)) ^ (lcol & 7)) << 4) +
                     ((lrow & 1) << 3) + (j << 1);
          *reinterpret_cast<unsigned int*>(pw + boff) = pack2(sv[n * 4 + j], sv[n * 4 + j + 1]);
        }
      asm volatile("s_waitcnt lgkmcnt(0)" ::: "memory");

      bf16x8 pf0 = *reinterpret_cast<const bf16x8*>(
          pw + (lcol << 7) + ((lrow ^ (lcol & 7)) << 4));
      bf16x8 pf1 = *reinterpret_cast<const bf16x8*>(
          pw + (lcol << 7) + (((4 + lrow) ^ (lcol & 7)) << 4));

      __builtin_amdgcn_s_setprio(1);
#pragma unroll
      for (int c = 0; c < 8; ++c) {
        const int d = c * 16 + lcol;
        bf16x8 vf0 = *reinterpret_cast<const bf16x8*>(
            &vbc[d * 64 + ((lrow ^ (lcol & 7)) << 3)]);
        o[c] = __builtin_amdgcn_mfma_f32_16x16x32_bf16(vf0, pf0, o[c], 0, 0, 0);
        bf16x8 vf1 = *reinterpret_cast<const bf16x8*>(
            &vbc[d * 64 + (((4 + lrow) ^ (lcol & 7)) << 3)]);
        o[c] = __builtin_amdgcn_mfma_f32_16x16x32_bf16(vf1, pf1, o[c], 0, 0, 0);
      }
      __builtin_amdgcn_s_setprio(0);
    }

    __syncthreads();
    cur ^= 1;
  }

  const float rl = 1.0f / l;
  const int trow = q0w + lcol;
#pragma unroll
  for (int c = 0; c < 8; ++c) {
    s16x4 st;
#pragma unroll
    for (int j = 0; j < 4; ++j) st[j] = (short)bfbits(o[c][j] * rl);
    *reinterpret_cast<s16x4*>(
        out + (size_t)(b * TSEQ + trow) * DMODEL + h * DHEAD + c * 16 + lrow * 4) = st;
  }
#undef STAGE_KV
}

// ---------------------------------------------------------------- launcher
extern "C" void kernel_launch(void* const* d_in, const int* in_sizes, int n_in,
                              void* d_out, int out_size, void* d_ws, size_t ws_size,
                              hipStream_t stream) {
  const float* x     = (const float*)d_in[0];
  const float* w_qkv = (const float*)d_in[1];
  const float* w_op  = (const float*)d_in[2];
  float* out = (float*)d_out;

  const size_t SZ_XB  = (size_t)4096 * 2048 * 2;
  const size_t SZ_WQ  = (size_t)6144 * 2048 * 2;
  const size_t SZ_WO  = (size_t)2048 * 2048 * 2;
  const size_t SZ_QKV = (size_t)4096 * 6144 * 2;
  const size_t SZ_VT  = (size_t)32 * 128 * 2048 * 2;
  const size_t SZ_AO  = (size_t)4096 * 2048 * 2;
  const size_t SZ_TAB = (size_t)2048 * 64 * 8;
  const size_t NEEDED = SZ_XB + SZ_WQ + SZ_WO + SZ_QKV + SZ_VT + SZ_AO + SZ_TAB;
  if (ws_size < NEEDED) return;

  char* p = (char*)d_ws;
  unsigned short* xb   = (unsigned short*)p; p += SZ_XB;
  unsigned short* wqb  = (unsigned short*)p; p += SZ_WQ;
  unsigned short* wob  = (unsigned short*)p; p += SZ_WO;
  unsigned short* qkv  = (unsigned short*)p; p += SZ_QKV;
  unsigned short* vt   = (unsigned short*)p; p += SZ_VT;
  unsigned short* ao   = (unsigned short*)p; p += SZ_AO;
  f32x2* cstab = (f32x2*)p; p += SZ_TAB;

  // fused prep: casts + RoPE tables in one launch
  prep_all<<<dim3(2048), dim3(256), 0, stream>>>(x, w_qkv, w_op, xb, wqb, wob, cstab);

  // qkv = x @ w_qkv^T with fused RoPE (+ q scale * log2e) on q,k thirds and
  // fused transposed V store (v third -> vt directly)
  gemm_bt<unsigned short, true, true><<<dim3(32, 48), dim3(256), 0, stream>>>(
      xb, wqb, qkv, 4096, 6144, 2048, cstab, vt);
  // causal flash attention (512 blocks, all-resident, CU-pair balanced)
  flash_attn<<<dim3(16, 16, 2), dim3(512), 0, stream>>>(qkv, vt, ao);
  // out = attn_out @ w_op^T
  gemm_bt<float, false, false><<<dim3(32, 16), dim3(256), 0, stream>>>(
      ao, wob, out, 4096, 2048, 2048, nullptr, nullptr);
}